// Round 3
// baseline (69.077 us; speedup 1.0000x reference)
//
#include <hip/hip_runtime.h>
#include <hip/hip_bf16.h>

#define NB 4
#define NN 256
#define ND 256
#define NK 1024
#define LOG2E 1.4426950408889634f
#define TRI_BLOCKS 2048

typedef __bf16 bf16x8 __attribute__((ext_vector_type(8)));
typedef float f32x4 __attribute__((ext_vector_type(4)));

__device__ __forceinline__ float blo(unsigned u) { return __uint_as_float(u << 16); }
__device__ __forceinline__ float bhi(unsigned u) { return __uint_as_float(u & 0xffff0000u); }

// h = g @ patterns (bf16 MFMA), fused epilogue: E = bf16(exp(beta*h)).
// Also zeroes the completion counter used by edge_final_kernel (every launch,
// so graph replay is deterministic).
__global__ __launch_bounds__(256) void gemm_exp_kernel(
    const float* __restrict__ A,   // g flattened (B*N, D) = (1024, 256)
    const float* __restrict__ P,   // patterns (D, K) = (256, 1024)
    const float* __restrict__ beta,
    ushort* __restrict__ E,        // (1024, 1024) bf16 bits
    unsigned* __restrict__ ctr) {
  if ((blockIdx.x | blockIdx.y) == 0 && threadIdx.x == 0) ctr[0] = 0u;
  const int lane = threadIdx.x & 63;
  const int w = threadIdx.x >> 6;
  const int m0 = blockIdx.x * 16;
  const int n0 = blockIdx.y * 64 + w * 16;
  const int r15 = lane & 15;
  const int g4 = lane >> 4;
  const int arow = m0 + r15;
  const int bcol = n0 + r15;

  f32x4 acc = {0.f, 0.f, 0.f, 0.f};
#pragma unroll
  for (int kk = 0; kk < ND; kk += 32) {
    const int kb = kk + g4 * 8;  // same (group,elem)->k map for A and B => layout-safe
    const float* ap = A + arow * ND + kb;
    const float4 a0 = *(const float4*)ap;
    const float4 a1 = *(const float4*)(ap + 4);
    const float* pp = P + kb * NK + bcol;
    bf16x8 af, bfr;
    af[0] = (__bf16)a0.x; af[1] = (__bf16)a0.y; af[2] = (__bf16)a0.z; af[3] = (__bf16)a0.w;
    af[4] = (__bf16)a1.x; af[5] = (__bf16)a1.y; af[6] = (__bf16)a1.z; af[7] = (__bf16)a1.w;
    bfr[0] = (__bf16)pp[0 * NK]; bfr[1] = (__bf16)pp[1 * NK];
    bfr[2] = (__bf16)pp[2 * NK]; bfr[3] = (__bf16)pp[3 * NK];
    bfr[4] = (__bf16)pp[4 * NK]; bfr[5] = (__bf16)pp[5 * NK];
    bfr[6] = (__bf16)pp[6 * NK]; bfr[7] = (__bf16)pp[7 * NK];
    acc = __builtin_amdgcn_mfma_f32_16x16x32_bf16(af, bfr, acc, 0, 0, 0);
  }
  const float c = beta[0] * LOG2E;
#pragma unroll
  for (int r = 0; r < 4; ++r) {
    const int orow = m0 + g4 * 4 + r;   // C/D: col = lane&15, row = (lane>>4)*4 + r (HW-verified)
    const float e = exp2f(c * acc[r]);
    const __bf16 v = (__bf16)e;
    E[orow * NK + bcol] = __builtin_bit_cast(unsigned short, v);
  }
}

// Fused: blocks [0,TRI_BLOCKS) triangles (long pole, dispatched first);
//        [TRI_BLOCKS, +256) gram G_b = E_b@E_b^T;  [TRI_BLOCKS+256, +512) g2.
__global__ __launch_bounds__(256) void fused_tgg_kernel(
    const ushort* __restrict__ E, const int* __restrict__ tris, const int m_tri,
    const float* __restrict__ g, float* __restrict__ G,
    float* __restrict__ pt, float* __restrict__ pg) {
  __shared__ float sp[4];
  const int lane = threadIdx.x & 63;
  const int w = threadIdx.x >> 6;
  const int bid = blockIdx.x;

  if (bid < TRI_BLOCKS) {
    // ---- triangles: one wave per (batch,tri), grid-stride ----
    const int nwaves = TRI_BLOCKS * 4;
    const int ntask = NB * m_tri;
    float lsum = 0.0f;
    for (int task = bid * 4 + w; task < ntask; task += nwaves) {
      const int b = task / m_tri;
      const int e = task - b * m_tri;
      const int v0 = tris[3 * e];
      const int v1 = tris[3 * e + 1];
      const int v2 = tris[3 * e + 2];
      const size_t base = ((size_t)b << 18);
      const uint4* r0 = (const uint4*)(E + base + ((size_t)v0 << 10));
      const uint4* r1 = (const uint4*)(E + base + ((size_t)v1 << 10));
      const uint4* r2 = (const uint4*)(E + base + ((size_t)v2 << 10));
      float s0 = 0.f, s1 = 0.f, s2 = 0.f, s3 = 0.f;
#pragma unroll
      for (int j = 0; j < 2; ++j) {
        const int idx = lane + j * 64;     // 128 uint4 per row, coalesced
        const uint4 ua = r0[idx];
        const uint4 ub = r1[idx];
        const uint4 uc = r2[idx];
        s0 = fmaf(blo(ua.x) * blo(ub.x), blo(uc.x), s0);
        s0 = fmaf(bhi(ua.x) * bhi(ub.x), bhi(uc.x), s0);
        s1 = fmaf(blo(ua.y) * blo(ub.y), blo(uc.y), s1);
        s1 = fmaf(bhi(ua.y) * bhi(ub.y), bhi(uc.y), s1);
        s2 = fmaf(blo(ua.z) * blo(ub.z), blo(uc.z), s2);
        s2 = fmaf(bhi(ua.z) * bhi(ub.z), bhi(uc.z), s2);
        s3 = fmaf(blo(ua.w) * blo(ub.w), blo(uc.w), s3);
        s3 = fmaf(bhi(ua.w) * bhi(ub.w), bhi(uc.w), s3);
      }
      float s = (s0 + s1) + (s2 + s3);
#pragma unroll
      for (int m = 32; m >= 1; m >>= 1) s += __shfl_xor(s, m, 64);
      lsum += logf(s);
    }
    if (lane == 0) sp[w] = lsum;
    __syncthreads();
    if (threadIdx.x == 0) pt[bid] = sp[0] + sp[1] + sp[2] + sp[3];
  } else if (bid < TRI_BLOCKS + 256) {
    // ---- gram: G_b = E_b @ E_b^T via bf16 MFMA ----
    const int gi = bid - TRI_BLOCKS;     // [0,256)
    const int b = gi >> 6;
    const int m0 = (gi & 15) * 16;
    const int n0 = ((gi >> 4) & 3) * 64 + w * 16;
    const int r15 = lane & 15;
    const int g4 = lane >> 4;
    const ushort* Eb = E + ((size_t)b << 18);
    const ushort* ar = Eb + (m0 + r15) * NK;
    const ushort* br = Eb + (n0 + r15) * NK;   // B[k][col] = E[col][k]
    f32x4 acc = {0.f, 0.f, 0.f, 0.f};
#pragma unroll
    for (int kk = 0; kk < NK; kk += 32) {
      const int kb = kk + g4 * 8;
      const bf16x8 af = *(const bf16x8*)(ar + kb);
      const bf16x8 bfr = *(const bf16x8*)(br + kb);  // same k-map => layout-safe
      acc = __builtin_amdgcn_mfma_f32_16x16x32_bf16(af, bfr, acc, 0, 0, 0);
    }
#pragma unroll
    for (int r = 0; r < 4; ++r) {
      const int orow = m0 + g4 * 4 + r;
      G[(size_t)(((b << 8) | orow) << 8) | (n0 + r15)] = acc[r];
    }
  } else {
    // ---- g2: sum(g*g) partials ----
    const int gi = bid - TRI_BLOCKS - 256;     // [0,256)
    const float4 v = ((const float4*)g)[gi * 256 + threadIdx.x];
    float s = v.x * v.x + v.y * v.y + v.z * v.z + v.w * v.w;
#pragma unroll
    for (int m = 32; m >= 1; m >>= 1) s += __shfl_xor(s, m, 64);
    if (lane == 0) sp[w] = s;
    __syncthreads();
    if (threadIdx.x == 0) pg[gi] = sp[0] + sp[1] + sp[2] + sp[3];
  }
}

// Edge lookups + partials; last block (device-scope counter) does final reduce.
__global__ __launch_bounds__(256) void edge_final_kernel(
    const float* __restrict__ G, const int* __restrict__ edges, const int m_edge,
    float* __restrict__ pe, const float* __restrict__ pt, const float* __restrict__ pg,
    const float* __restrict__ beta, const int ns,
    unsigned* __restrict__ ctr, float* __restrict__ out) {
  __shared__ float sp[4];
  const int t = blockIdx.x * 256 + threadIdx.x;
  float v = 0.0f;
  if (t < NB * m_edge) {
    const int b = t / m_edge;
    const int e = t - b * m_edge;
    const int v0 = edges[2 * e];
    const int v1 = edges[2 * e + 1];
    v = logf(G[(size_t)(((b << 8) | v0) << 8) | v1]);
  }
#pragma unroll
  for (int m = 32; m >= 1; m >>= 1) v += __shfl_xor(v, m, 64);
  const int lane = threadIdx.x & 63;
  const int w = threadIdx.x >> 6;
  if (lane == 0) sp[w] = v;
  __syncthreads();
  if (threadIdx.x == 0) pe[blockIdx.x] = sp[0] + sp[1] + sp[2] + sp[3];
  __threadfence();
  __syncthreads();
  __shared__ bool is_last;
  if (threadIdx.x == 0) {
    const unsigned old = atomicAdd(ctr, 1u);
    is_last = (old == gridDim.x - 1);
  }
  __syncthreads();
  if (!is_last) return;
  __threadfence();
  // final reduction: pe[gridDim.x] + pt[TRI_BLOCKS] -> L ; pg[256] -> Gg
  float sl = 0.f, sg = 0.f;
  for (int i = threadIdx.x; i < (int)gridDim.x; i += 256) sl += pe[i];
  for (int i = threadIdx.x; i < TRI_BLOCKS; i += 256) sl += pt[i];
  if (threadIdx.x < 256) { /* pg has 256 entries */ }
  sg = pg[threadIdx.x];
#pragma unroll
  for (int m = 32; m >= 1; m >>= 1) {
    sl += __shfl_xor(sl, m, 64);
    sg += __shfl_xor(sg, m, 64);
  }
  __shared__ float sa[4], sb[4];
  if (lane == 0) { sa[w] = sl; sb[w] = sg; }
  __syncthreads();
  if (threadIdx.x == 0) {
    const float L = sa[0] + sa[1] + sa[2] + sa[3];
    const float Gg = sb[0] + sb[1] + sb[2] + sb[3];
    const float ep = -(1.0f / (beta[0] * (float)ns)) * L;
    out[0] = (ep - 2.0f * Gg) / (float)(NB * NN);
  }
}

extern "C" void kernel_launch(void* const* d_in, const int* in_sizes, int n_in,
                              void* d_out, int out_size, void* d_ws, size_t ws_size,
                              hipStream_t stream) {
  const float* g = (const float*)d_in[0];
  const float* patterns = (const float*)d_in[1];
  const float* beta = (const float*)d_in[2];
  const int* edges = (const int*)d_in[3];
  const int* triangles = (const int*)d_in[4];
  const int m_edge = in_sizes[3] / 2;   // 16320
  const int m_tri = in_sizes[4] / 3;    // 16320
  const int ns = m_edge + m_tri;

  // ws: E 2MB | G 1MB | pe[1024] | pt[2048] | pg[256] | ctr
  ushort* E = (ushort*)d_ws;
  float* G = (float*)((char*)d_ws + (2u << 20));
  float* pe = (float*)((char*)d_ws + (3u << 20));
  float* pt = pe + 1024;
  float* pg = pt + TRI_BLOCKS;
  unsigned* ctr = (unsigned*)(pg + 256);
  float* out = (float*)d_out;

  hipLaunchKernelGGL(gemm_exp_kernel, dim3(64, 16), dim3(256), 0, stream,
                     g, patterns, beta, E, ctr);
  hipLaunchKernelGGL(fused_tgg_kernel, dim3(TRI_BLOCKS + 512), dim3(256), 0, stream,
                     E, triangles, m_tri, g, G, pt, pg);
  const int eblocks = (NB * m_edge + 255) / 256;   // 255
  hipLaunchKernelGGL(edge_final_kernel, dim3(eblocks), dim3(256), 0, stream,
                     G, edges, m_edge, pe, pt, pg, beta, ns, ctr, out);
}

// Round 4
// 43.789 us; speedup vs baseline: 1.5775x; 1.5775x over previous
//
#include <hip/hip_runtime.h>
#include <hip/hip_bf16.h>

#define NB 4
#define NN 256
#define ND 256
#define NK 1024
#define LOG2E 1.4426950408889634f

#define EDGE_BLOCKS 800
#define TRI_BLOCKS 1216
#define G2_BLOCKS 32
#define LSE_BLOCKS (EDGE_BLOCKS + TRI_BLOCKS)   // 2016
#define K2_BLOCKS (LSE_BLOCKS + G2_BLOCKS)      // 2048 = 8 blocks/CU exactly

typedef __bf16 bf16x8 __attribute__((ext_vector_type(8)));
typedef float f32x4 __attribute__((ext_vector_type(4)));
typedef float f32x2 __attribute__((ext_vector_type(2)));

// ---- fp8 helpers (OCP e4m3 on gfx950; K1 encodes with the same HW cvt that
// K2 decodes, so the pair is self-consistent) ----
__device__ __forceinline__ void dot4_fp8(unsigned a, unsigned b,
                                         float& s0, float& s1) {
  const f32x2 a0 = __builtin_amdgcn_cvt_pk_f32_fp8(a, false);
  const f32x2 a1 = __builtin_amdgcn_cvt_pk_f32_fp8(a, true);
  const f32x2 b0 = __builtin_amdgcn_cvt_pk_f32_fp8(b, false);
  const f32x2 b1 = __builtin_amdgcn_cvt_pk_f32_fp8(b, true);
  s0 = fmaf(a0[0], b0[0], s0);
  s1 = fmaf(a0[1], b0[1], s1);
  s0 = fmaf(a1[0], b1[0], s0);
  s1 = fmaf(a1[1], b1[1], s1);
}

__device__ __forceinline__ void tdot4_fp8(unsigned a, unsigned b, unsigned c,
                                          float& s0, float& s1) {
  const f32x2 a0 = __builtin_amdgcn_cvt_pk_f32_fp8(a, false);
  const f32x2 a1 = __builtin_amdgcn_cvt_pk_f32_fp8(a, true);
  const f32x2 b0 = __builtin_amdgcn_cvt_pk_f32_fp8(b, false);
  const f32x2 b1 = __builtin_amdgcn_cvt_pk_f32_fp8(b, true);
  const f32x2 c0 = __builtin_amdgcn_cvt_pk_f32_fp8(c, false);
  const f32x2 c1 = __builtin_amdgcn_cvt_pk_f32_fp8(c, true);
  s0 = fmaf(a0[0] * b0[0], c0[0], s0);
  s1 = fmaf(a0[1] * b0[1], c0[1], s1);
  s0 = fmaf(a1[0] * b1[0], c1[0], s0);
  s1 = fmaf(a1[1] * b1[1], c1[1], s1);
}

__device__ __forceinline__ float wave_reduce(float s) {
#pragma unroll
  for (int m = 32; m >= 1; m >>= 1) s += __shfl_xor(s, m, 64);
  return s;
}

// K1: h = g @ patterns (bf16 MFMA), epilogue E8 = fp8(exp(beta*h))
__global__ __launch_bounds__(256) void gemm_exp_kernel(
    const float* __restrict__ A,   // g flattened (B*N, D) = (1024, 256)
    const float* __restrict__ P,   // patterns (D, K) = (256, 1024)
    const float* __restrict__ beta,
    unsigned char* __restrict__ E8) {  // (1024, 1024) fp8
  const int lane = threadIdx.x & 63;
  const int w = threadIdx.x >> 6;
  const int m0 = blockIdx.x * 16;
  const int n0 = blockIdx.y * 64 + w * 16;
  const int r15 = lane & 15;
  const int g4 = lane >> 4;
  const int arow = m0 + r15;
  const int bcol = n0 + r15;

  f32x4 acc = {0.f, 0.f, 0.f, 0.f};
#pragma unroll
  for (int kk = 0; kk < ND; kk += 32) {
    const int kb = kk + g4 * 8;  // same (group,elem)->k map for A and B => layout-safe
    const float* ap = A + arow * ND + kb;
    const float4 a0 = *(const float4*)ap;
    const float4 a1 = *(const float4*)(ap + 4);
    const float* pp = P + kb * NK + bcol;
    bf16x8 af, bfr;
    af[0] = (__bf16)a0.x; af[1] = (__bf16)a0.y; af[2] = (__bf16)a0.z; af[3] = (__bf16)a0.w;
    af[4] = (__bf16)a1.x; af[5] = (__bf16)a1.y; af[6] = (__bf16)a1.z; af[7] = (__bf16)a1.w;
    bfr[0] = (__bf16)pp[0 * NK]; bfr[1] = (__bf16)pp[1 * NK];
    bfr[2] = (__bf16)pp[2 * NK]; bfr[3] = (__bf16)pp[3 * NK];
    bfr[4] = (__bf16)pp[4 * NK]; bfr[5] = (__bf16)pp[5 * NK];
    bfr[6] = (__bf16)pp[6 * NK]; bfr[7] = (__bf16)pp[7 * NK];
    acc = __builtin_amdgcn_mfma_f32_16x16x32_bf16(af, bfr, acc, 0, 0, 0);
  }
  const float c = beta[0] * LOG2E;
#pragma unroll
  for (int r = 0; r < 4; ++r) {
    const int orow = m0 + g4 * 4 + r;   // C/D: col = lane&15, row = (lane>>4)*4 + r (HW-verified)
    const float e = exp2f(c * acc[r]);
    const int p = __builtin_amdgcn_cvt_pk_fp8_f32(e, e, 0, false);
    E8[orow * NK + bcol] = (unsigned char)(p & 0xff);
  }
}

// K2: fused edges + triangles + g2. Block-partitioned, grid-stride per path,
// per-block partials only (no atomics, no device fences).
__global__ __launch_bounds__(256, 8) void fused_simplex_kernel(
    const unsigned char* __restrict__ E8,
    const int* __restrict__ edges, const int m_edge,
    const int* __restrict__ tris, const int m_tri,
    const float* __restrict__ g,
    float* __restrict__ pl, float* __restrict__ pg2) {
  __shared__ float sp[4];
  const int lane = threadIdx.x & 63;
  const int w = threadIdx.x >> 6;
  const int bid = blockIdx.x;

  if (bid < EDGE_BLOCKS) {
    // ---- edges: lse = ln( dot(E8[b,v0,:], E8[b,v1,:]) ), one wave/task ----
    const int nwaves = EDGE_BLOCKS * 4;
    const int ntask = NB * m_edge;
    float lsum = 0.0f;
    for (int task = bid * 4 + w; task < ntask; task += nwaves) {
      const int b = task / m_edge;
      const int e = task - b * m_edge;
      const int v0 = edges[2 * e];
      const int v1 = edges[2 * e + 1];
      const size_t base = ((size_t)b << 18);   // b*256*1024 bytes
      const uint4 ua = ((const uint4*)(E8 + base + ((size_t)v0 << 10)))[lane];
      const uint4 ub = ((const uint4*)(E8 + base + ((size_t)v1 << 10)))[lane];
      float s0 = 0.f, s1 = 0.f;
      dot4_fp8(ua.x, ub.x, s0, s1);
      dot4_fp8(ua.y, ub.y, s0, s1);
      dot4_fp8(ua.z, ub.z, s0, s1);
      dot4_fp8(ua.w, ub.w, s0, s1);
      const float s = wave_reduce(s0 + s1);
      lsum += __logf(s);
    }
    if (lane == 0) sp[w] = lsum;
    __syncthreads();
    if (threadIdx.x == 0) pl[bid] = sp[0] + sp[1] + sp[2] + sp[3];
  } else if (bid < LSE_BLOCKS) {
    // ---- triangles: lse = ln( sum_k E0*E1*E2 ), one wave/task ----
    const int nwaves = TRI_BLOCKS * 4;
    const int ntask = NB * m_tri;
    float lsum = 0.0f;
    for (int task = (bid - EDGE_BLOCKS) * 4 + w; task < ntask; task += nwaves) {
      const int b = task / m_tri;
      const int e = task - b * m_tri;
      const int v0 = tris[3 * e];
      const int v1 = tris[3 * e + 1];
      const int v2 = tris[3 * e + 2];
      const size_t base = ((size_t)b << 18);
      const uint4 ua = ((const uint4*)(E8 + base + ((size_t)v0 << 10)))[lane];
      const uint4 ub = ((const uint4*)(E8 + base + ((size_t)v1 << 10)))[lane];
      const uint4 uc = ((const uint4*)(E8 + base + ((size_t)v2 << 10)))[lane];
      float s0 = 0.f, s1 = 0.f;
      tdot4_fp8(ua.x, ub.x, uc.x, s0, s1);
      tdot4_fp8(ua.y, ub.y, uc.y, s0, s1);
      tdot4_fp8(ua.z, ub.z, uc.z, s0, s1);
      tdot4_fp8(ua.w, ub.w, uc.w, s0, s1);
      const float s = wave_reduce(s0 + s1);
      lsum += __logf(s);
    }
    if (lane == 0) sp[w] = lsum;
    __syncthreads();
    if (threadIdx.x == 0) pl[bid] = sp[0] + sp[1] + sp[2] + sp[3];
  } else {
    // ---- g2: sum(g*g) partials, 32 blocks x 8 float4/thread ----
    const int gi = bid - LSE_BLOCKS;
    float s = 0.0f;
    for (int i = gi * 256 + threadIdx.x; i < 65536; i += G2_BLOCKS * 256) {
      const float4 v = ((const float4*)g)[i];
      s += v.x * v.x + v.y * v.y + v.z * v.z + v.w * v.w;
    }
    s = wave_reduce(s);
    if (lane == 0) sp[w] = s;
    __syncthreads();
    if (threadIdx.x == 0) pg2[gi] = sp[0] + sp[1] + sp[2] + sp[3];
  }
}

// K3: single-block final reduction
__global__ __launch_bounds__(256) void final_kernel(
    const float* __restrict__ pl, const float* __restrict__ pg2,
    const float* __restrict__ beta, const int ns, float* __restrict__ out) {
  __shared__ float sa[4], sb[4];
  float sl = 0.f, sg = 0.f;
  for (int i = threadIdx.x; i < LSE_BLOCKS; i += 256) sl += pl[i];
  if (threadIdx.x < G2_BLOCKS) sg = pg2[threadIdx.x];
  sl = wave_reduce(sl);
  sg = wave_reduce(sg);
  const int lane = threadIdx.x & 63;
  const int w = threadIdx.x >> 6;
  if (lane == 0) { sa[w] = sl; sb[w] = sg; }
  __syncthreads();
  if (threadIdx.x == 0) {
    const float L = sa[0] + sa[1] + sa[2] + sa[3];
    const float Gg = sb[0] + sb[1] + sb[2] + sb[3];
    const float ep = -(1.0f / (beta[0] * (float)ns)) * L;
    out[0] = (ep - 2.0f * Gg) / (float)(NB * NN);
  }
}

extern "C" void kernel_launch(void* const* d_in, const int* in_sizes, int n_in,
                              void* d_out, int out_size, void* d_ws, size_t ws_size,
                              hipStream_t stream) {
  const float* g = (const float*)d_in[0];
  const float* patterns = (const float*)d_in[1];
  const float* beta = (const float*)d_in[2];
  const int* edges = (const int*)d_in[3];
  const int* triangles = (const int*)d_in[4];
  const int m_edge = in_sizes[3] / 2;   // 16320
  const int m_tri = in_sizes[4] / 3;    // 16320
  const int ns = m_edge + m_tri;

  // ws: E8 1MB | pl[2016] | pg2[32]
  unsigned char* E8 = (unsigned char*)d_ws;
  float* pl = (float*)((char*)d_ws + (1u << 20));
  float* pg2 = pl + LSE_BLOCKS;
  float* out = (float*)d_out;

  hipLaunchKernelGGL(gemm_exp_kernel, dim3(64, 16), dim3(256), 0, stream,
                     g, patterns, beta, E8);
  hipLaunchKernelGGL(fused_simplex_kernel, dim3(K2_BLOCKS), dim3(256), 0, stream,
                     E8, edges, m_edge, triangles, m_tri, g, pl, pg2);
  hipLaunchKernelGGL(final_kernel, dim3(1), dim3(256), 0, stream,
                     pl, pg2, beta, ns, out);
}